// Round 1
// baseline (236.493 us; speedup 1.0000x reference)
//
#include <hip/hip_runtime.h>
#include <math.h>

#define N_LAYERS 200
#define KSIZE 7
#define L_IN 1388
#define FC_IN 188
#define FC_OUT 91
#define NTHREADS 256

__global__ __launch_bounds__(NTHREADS) void conv_chain_kernel(
    const float* __restrict__ x,
    const float* __restrict__ conv_w,
    const float* __restrict__ conv_b,
    const float* __restrict__ fc_w,
    const float* __restrict__ fc_b,
    float* __restrict__ out)
{
    __shared__ float bufA[L_IN];
    __shared__ float bufB[L_IN];
    __shared__ float wts[N_LAYERS * KSIZE];
    __shared__ float bias[N_LAYERS];

    const int tid = threadIdx.x;
    const int row = blockIdx.x;

    // Stage conv weights/biases into LDS (uniform-broadcast reads later).
    for (int i = tid; i < N_LAYERS * KSIZE; i += NTHREADS) wts[i] = conv_w[i];
    for (int i = tid; i < N_LAYERS; i += NTHREADS) bias[i] = conv_b[i];

    // Stage this row into LDS (coalesced).
    const float* xr = x + (size_t)row * L_IN;
    for (int j = tid; j < L_IN; j += NTHREADS) bufA[j] = xr[j];
    __syncthreads();

    float* cur = bufA;
    float* nxt = bufB;
    int L = L_IN;

    for (int i = 0; i < N_LAYERS; ++i) {
        const int Lout = L - (KSIZE - 1);
        const float w0 = wts[i * KSIZE + 0];
        const float w1 = wts[i * KSIZE + 1];
        const float w2 = wts[i * KSIZE + 2];
        const float w3 = wts[i * KSIZE + 3];
        const float w4 = wts[i * KSIZE + 4];
        const float w5 = wts[i * KSIZE + 5];
        const float w6 = wts[i * KSIZE + 6];
        const float b  = bias[i];
        const bool do_relu = (i < N_LAYERS - 1);

        // Each thread owns a contiguous chunk of G outputs: reads G+6
        // contiguous LDS floats instead of 7*G strided ones.
        const int G = (Lout + NTHREADS - 1) >> 8;  // 1..6
        int j0 = tid * G;
        int j1 = j0 + G;
        if (j1 > Lout) j1 = Lout;
        for (int j = j0; j < j1; ++j) {
            float acc = fmaf(w0, cur[j + 0], b);
            acc = fmaf(w1, cur[j + 1], acc);
            acc = fmaf(w2, cur[j + 2], acc);
            acc = fmaf(w3, cur[j + 3], acc);
            acc = fmaf(w4, cur[j + 4], acc);
            acc = fmaf(w5, cur[j + 5], acc);
            acc = fmaf(w6, cur[j + 6], acc);
            nxt[j] = do_relu ? fmaxf(acc, 0.0f) : acc;
        }
        __syncthreads();
        float* t = cur; cur = nxt; nxt = t;
        L = Lout;
    }

    // cur[] now holds FC_IN = 188 floats. FC(188 -> 91) + sigmoid.
    if (tid < FC_OUT) {
        const float* wrow = fc_w + tid * FC_IN;
        float acc = fc_b[tid];
#pragma unroll 4
        for (int j = 0; j < FC_IN; ++j)
            acc = fmaf(wrow[j], cur[j], acc);
        out[(size_t)row * FC_OUT + tid] = 1.0f / (1.0f + expf(-acc));
    }
}

extern "C" void kernel_launch(void* const* d_in, const int* in_sizes, int n_in,
                              void* d_out, int out_size, void* d_ws, size_t ws_size,
                              hipStream_t stream) {
    const float* x      = (const float*)d_in[0];
    const float* conv_w = (const float*)d_in[1];
    const float* conv_b = (const float*)d_in[2];
    const float* fc_w   = (const float*)d_in[3];
    const float* fc_b   = (const float*)d_in[4];
    float* outp = (float*)d_out;

    const int batch = in_sizes[0] / L_IN;  // 1024
    conv_chain_kernel<<<batch, NTHREADS, 0, stream>>>(x, conv_w, conv_b, fc_w, fc_b, outp);
}

// Round 2
// 161.227 us; speedup vs baseline: 1.4668x; 1.4668x over previous
//
#include <hip/hip_runtime.h>
#include <math.h>

#define N_LAYERS 200
#define KSIZE 7
#define L_IN 1388
#define FC_IN 188
#define FC_OUT 91
#define RPT 22   // values per lane: 64*22 = 1408 >= 1388

// In-place conv step over a lane's RPT contiguous values.
// h[0..5] = next lane's r[0..5], captured BEFORE any lane updates.
// Ascending in-place update is safe: output k overwrites input k, which
// no output k' > k ever reads (they read positions >= k' > k).
template<bool RELU>
__device__ __forceinline__ void conv_step(float r[RPT], const float h[6],
                                          const float w[KSIZE], float b) {
#pragma unroll
    for (int k = 0; k < RPT; ++k) {
        float acc = b;
#pragma unroll
        for (int d = 0; d < KSIZE; ++d) {
            const int m = k + d;
            const float v = (m < RPT) ? r[m] : h[m - RPT];  // compile-time select
            acc = fmaf(w[d], v, acc);
        }
        r[k] = RELU ? fmaxf(acc, 0.0f) : acc;
    }
}

__global__ __launch_bounds__(64) void conv_chain_kernel(
    const float* __restrict__ x,
    const float* __restrict__ conv_w,
    const float* __restrict__ conv_b,
    const float* __restrict__ fc_w,
    const float* __restrict__ fc_b,
    float* __restrict__ out)
{
    const int row  = blockIdx.x;
    const int lane = threadIdx.x;   // block = 1 wave of 64
    const int base = lane * RPT;

    // Load this lane's chunk of the row into registers; zero-pad the tail.
    float r[RPT];
    const float* xr = x + (size_t)row * L_IN;
#pragma unroll
    for (int k = 0; k < RPT; ++k) {
        const int p = base + k;
        r[k] = (p < L_IN) ? xr[p] : 0.0f;
    }

    // Weights for layer 0 (uniform -> scalar loads); prefetch one layer ahead.
    float w[KSIZE], b;
#pragma unroll
    for (int d = 0; d < KSIZE; ++d) w[d] = conv_w[d];
    b = conv_b[0];

#pragma unroll 1
    for (int i = 0; i < N_LAYERS - 1; ++i) {
        float wn[KSIZE], bn;
#pragma unroll
        for (int d = 0; d < KSIZE; ++d) wn[d] = conv_w[(i + 1) * KSIZE + d];
        bn = conv_b[i + 1];

        float h[6];
#pragma unroll
        for (int t = 0; t < 6; ++t) h[t] = __shfl_down(r[t], 1);

        conv_step<true>(r, h, w, b);

#pragma unroll
        for (int d = 0; d < KSIZE; ++d) w[d] = wn[d];
        b = bn;
    }
    {   // final layer: no ReLU
        float h[6];
#pragma unroll
        for (int t = 0; t < 6; ++t) h[t] = __shfl_down(r[t], 1);
        conv_step<false>(r, h, w, b);
    }

    // FC(188 -> 91) + sigmoid. Stage the 188 results (lanes 0..8) in LDS,
    // then broadcast-read (same address across lanes -> conflict-free).
    __shared__ __align__(16) float hs[FC_IN];
#pragma unroll
    for (int k = 0; k < RPT; ++k) {
        const int p = base + k;
        if (p < FC_IN) hs[p] = r[k];
    }
    __syncthreads();  // single wave: compiles to waitcnt + cheap barrier

    const int o1  = lane + 64;
    const int o1c = (o1 < FC_OUT) ? o1 : (FC_OUT - 1);
    float acc0 = fc_b[lane];            // lane < 64 < 91: always a valid output
    float acc1 = fc_b[o1c];
    const float4* w0p = (const float4*)(fc_w + lane * FC_IN);  // 188*4B = 16B-aligned rows
    const float4* w1p = (const float4*)(fc_w + o1c * FC_IN);
    const float4* hp  = (const float4*)hs;
#pragma unroll 4
    for (int q = 0; q < FC_IN / 4; ++q) {
        const float4 hv = hp[q];
        const float4 wa = w0p[q];
        const float4 wb = w1p[q];
        acc0 = fmaf(wa.x, hv.x, acc0); acc0 = fmaf(wa.y, hv.y, acc0);
        acc0 = fmaf(wa.z, hv.z, acc0); acc0 = fmaf(wa.w, hv.w, acc0);
        acc1 = fmaf(wb.x, hv.x, acc1); acc1 = fmaf(wb.y, hv.y, acc1);
        acc1 = fmaf(wb.z, hv.z, acc1); acc1 = fmaf(wb.w, hv.w, acc1);
    }
    float* orow = out + (size_t)row * FC_OUT;
    orow[lane] = 1.0f / (1.0f + expf(-acc0));
    if (o1 < FC_OUT) orow[o1] = 1.0f / (1.0f + expf(-acc1));
}

extern "C" void kernel_launch(void* const* d_in, const int* in_sizes, int n_in,
                              void* d_out, int out_size, void* d_ws, size_t ws_size,
                              hipStream_t stream) {
    const float* x      = (const float*)d_in[0];
    const float* conv_w = (const float*)d_in[1];
    const float* conv_b = (const float*)d_in[2];
    const float* fc_w   = (const float*)d_in[3];
    const float* fc_b   = (const float*)d_in[4];
    float* outp = (float*)d_out;

    const int batch = in_sizes[0] / L_IN;  // 1024 rows, one wave each
    conv_chain_kernel<<<batch, 64, 0, stream>>>(x, conv_w, conv_b, fc_w, fc_b, outp);
}

// Round 3
// 145.056 us; speedup vs baseline: 1.6304x; 1.1115x over previous
//
#include <hip/hip_runtime.h>
#include <math.h>

#define N_LAYERS 200
#define KSIZE 7
#define L_IN 1388
#define FC_IN 188
#define FC_OUT 91
#define RMAX 22   // stage-0 values per lane: 64*22 = 1408 >= 1388

// One stage of layers [i0,i1) with R values/lane, software-pipelined halo.
// Invariants:
//  - r[0..R-1] holds positions lane*R + k of the current layer's input.
//  - h[0..5]   holds positions lane*R + R + t (the 6-value halo) of the
//              current layer's input, fetched during the PREVIOUS layer.
//  - Ascending in-place update: output k overwrites input k, never read
//    again by outputs k' > k (they read positions >= k').
//  - After updating r[0..5] they are the NEXT layer's inputs at those
//    positions, so the shfl for the next layer's halo issues right there,
//    and its latency is hidden behind the k=6..R-1 updates.
template<int R, bool RELU>
__device__ __forceinline__ void run_stage(float (&r)[RMAX], float (&h)[6],
                                          const float* __restrict__ cw,
                                          const float* __restrict__ cb,
                                          int i0, int i1)
{
    constexpr int S = (R < 6) ? R : 6;  // split point: first S updates, then shfl
    float w[KSIZE], b;
#pragma unroll
    for (int d = 0; d < KSIZE; ++d) w[d] = cw[i0 * KSIZE + d];
    b = cb[i0];

#pragma unroll 1
    for (int i = i0; i < i1; ++i) {
        // --- update k = 0..S-1 (may consume h when R < 12) ---
#pragma unroll
        for (int k = 0; k < S; ++k) {
            float acc = b;
#pragma unroll
            for (int d = 0; d < KSIZE; ++d) {
                const int m = k + d;
                const float v = (m < R) ? r[m] : h[m - R];  // compile-time select
                acc = fmaf(w[d], v, acc);
            }
            r[k] = RELU ? fmaxf(acc, 0.0f) : acc;
        }

        // --- issue next layer's halo fetch (reads the JUST-updated r[0..5]
        //     of lane+1 [+2 for R<6]; single-wave lockstep makes this exact) ---
        float hn[6];
#pragma unroll
        for (int t = 0; t < 6; ++t)
            hn[t] = __shfl_down(r[t % R], 1 + t / R);

        // --- prefetch next layer's weights (uniform -> scalar loads) ---
        float w2[KSIZE], b2;
        if (i + 1 < i1) {
#pragma unroll
            for (int d = 0; d < KSIZE; ++d) w2[d] = cw[(i + 1) * KSIZE + d];
            b2 = cb[i + 1];
        } else {
#pragma unroll
            for (int d = 0; d < KSIZE; ++d) w2[d] = w[d];
            b2 = b;
        }

        // --- update k = S..R-1 (consumes h fetched one layer ago) ---
#pragma unroll
        for (int k = S; k < R; ++k) {
            float acc = b;
#pragma unroll
            for (int d = 0; d < KSIZE; ++d) {
                const int m = k + d;
                const float v = (m < R) ? r[m] : h[m - R];
                acc = fmaf(w[d], v, acc);
            }
            r[k] = RELU ? fmaxf(acc, 0.0f) : acc;
        }

        // --- commit pipelined state ---
#pragma unroll
        for (int t = 0; t < 6; ++t) h[t] = hn[t];
#pragma unroll
        for (int d = 0; d < KSIZE; ++d) w[d] = w2[d];
        b = b2;
    }
}

// Re-distribute from R_old values/lane to R_new, and re-prime the halo
// straight from LDS. Single wave => lockstep => __syncthreads is just a
// cheap waitcnt+barrier.
template<int Ro, int Rn>
__device__ __forceinline__ void repack(float (&r)[RMAX], float (&h)[6],
                                       float* lbuf, int lane)
{
#pragma unroll
    for (int k = 0; k < Ro; ++k) lbuf[lane * Ro + k] = r[k];
    __syncthreads();
#pragma unroll
    for (int k = 0; k < Rn; ++k) r[k] = lbuf[lane * Rn + k];
#pragma unroll
    for (int t = 0; t < 6; ++t) h[t] = lbuf[lane * Rn + Rn + t];
    __syncthreads();
}

__global__ __launch_bounds__(64) void conv_chain_kernel(
    const float* __restrict__ x,
    const float* __restrict__ conv_w,
    const float* __restrict__ conv_b,
    const float* __restrict__ fc_w,
    const float* __restrict__ fc_b,
    float* __restrict__ out)
{
    __shared__ __align__(16) float lbuf[64 * RMAX];  // 5.5 KB; reused for FC stage

    const int row  = blockIdx.x;
    const int lane = threadIdx.x;   // block = 1 wave of 64
    const int base = lane * RMAX;

    // Load chunk + initial halo from global; zero-pad past L_IN.
    float r[RMAX], h[6];
    const float* xr = x + (size_t)row * L_IN;
#pragma unroll
    for (int k = 0; k < RMAX; ++k) {
        const int p = base + k;
        r[k] = (p < L_IN) ? xr[p] : 0.0f;
    }
#pragma unroll
    for (int t = 0; t < 6; ++t) {
        const int p = base + RMAX + t;
        h[t] = (p < L_IN) ? xr[p] : 0.0f;
    }

    // 7 stages; R shrinks with the valid length (len_i = 1388 - 6i):
    // layer 32: 1196 <= 64*19; 64: 1004 <= 64*16; 96: 812 <= 64*13;
    // 128: 620 <= 64*10; 160: 428 <= 64*7; 192: 236 <= 64*4.
    run_stage<22, true>(r, h, conv_w, conv_b,   0,  32);
    repack<22, 19>(r, h, lbuf, lane);
    run_stage<19, true>(r, h, conv_w, conv_b,  32,  64);
    repack<19, 16>(r, h, lbuf, lane);
    run_stage<16, true>(r, h, conv_w, conv_b,  64,  96);
    repack<16, 13>(r, h, lbuf, lane);
    run_stage<13, true>(r, h, conv_w, conv_b,  96, 128);
    repack<13, 10>(r, h, lbuf, lane);
    run_stage<10, true>(r, h, conv_w, conv_b, 128, 160);
    repack<10, 7>(r, h, lbuf, lane);
    run_stage< 7, true>(r, h, conv_w, conv_b, 160, 192);
    repack< 7, 4>(r, h, lbuf, lane);
    run_stage< 4, true >(r, h, conv_w, conv_b, 192, 199);
    run_stage< 4, false>(r, h, conv_w, conv_b, 199, 200);  // last layer: no ReLU

    // FC(188 -> 91) + sigmoid. r is in R=4 layout: position lane*4 + k.
    float* hs = lbuf;  // reuse LDS
#pragma unroll
    for (int k = 0; k < 4; ++k) {
        const int p = lane * 4 + k;
        if (p < FC_IN) hs[p] = r[k];
    }
    __syncthreads();

    const int o1  = lane + 64;
    const int o1c = (o1 < FC_OUT) ? o1 : (FC_OUT - 1);
    float acc0 = fc_b[lane];            // lane < 64 < 91: always valid
    float acc1 = fc_b[o1c];
    const float4* w0p = (const float4*)(fc_w + lane * FC_IN);  // 188*4B rows: 16B-aligned
    const float4* w1p = (const float4*)(fc_w + o1c * FC_IN);
    const float4* hp  = (const float4*)hs;
#pragma unroll 4
    for (int q = 0; q < FC_IN / 4; ++q) {
        const float4 hv = hp[q];
        const float4 wa = w0p[q];
        const float4 wb = w1p[q];
        acc0 = fmaf(wa.x, hv.x, acc0); acc0 = fmaf(wa.y, hv.y, acc0);
        acc0 = fmaf(wa.z, hv.z, acc0); acc0 = fmaf(wa.w, hv.w, acc0);
        acc1 = fmaf(wb.x, hv.x, acc1); acc1 = fmaf(wb.y, hv.y, acc1);
        acc1 = fmaf(wb.z, hv.z, acc1); acc1 = fmaf(wb.w, hv.w, acc1);
    }
    float* orow = out + (size_t)row * FC_OUT;
    orow[lane] = 1.0f / (1.0f + expf(-acc0));
    if (o1 < FC_OUT) orow[o1] = 1.0f / (1.0f + expf(-acc1));
}

extern "C" void kernel_launch(void* const* d_in, const int* in_sizes, int n_in,
                              void* d_out, int out_size, void* d_ws, size_t ws_size,
                              hipStream_t stream) {
    const float* x      = (const float*)d_in[0];
    const float* conv_w = (const float*)d_in[1];
    const float* conv_b = (const float*)d_in[2];
    const float* fc_w   = (const float*)d_in[3];
    const float* fc_b   = (const float*)d_in[4];
    float* outp = (float*)d_out;

    const int batch = in_sizes[0] / L_IN;  // 1024 rows, one wave each
    conv_chain_kernel<<<batch, 64, 0, stream>>>(x, conv_w, conv_b, fc_w, fc_b, outp);
}

// Round 4
// 140.852 us; speedup vs baseline: 1.6790x; 1.0298x over previous
//
#include <hip/hip_runtime.h>
#include <math.h>

#define N_LAYERS 200
#define KSIZE 7
#define L_IN 1388
#define FC_IN 188
#define FC_OUT 91
#define NT 128        // 2 waves per row
#define RMAX 11       // stage-0 values per thread: 128*11 = 1408 >= 1388
#define HSTRIDE 8     // floats per thread slot in halo ring (32B-aligned slots)

// One stage of layers [i0,i1) with R values/thread.
// Invariants:
//  - r[0..R-1] holds positions tid*R + k of the current layer's input.
//  - h[0..5]   holds positions tid*R + R + t of the current layer's input,
//              fetched from the LDS halo ring during the PREVIOUS layer.
//  - Per layer: update r[0..S-1] (S=min(6,R)) -> publish them to the halo
//    ring (parity i&1) -> barrier -> read next layer's halo -> update the
//    rest. Double-buffered ring + per-layer barrier is race-free: a thread
//    can only write parity p again after passing a barrier that the reader
//    of the previous parity-p values has also passed.
//  - Ascending in-place update is safe: output k overwrites input k, which
//    no later output reads.
template<int R, bool RELU>
__device__ __forceinline__ void run_stage(float (&r)[RMAX], float (&h)[6],
                                          const float* __restrict__ cw,
                                          const float* __restrict__ cb,
                                          int i0, int i1,
                                          float (*hbuf)[(NT + 2) * HSTRIDE],
                                          int tid)
{
    constexpr int S = (R < 6) ? R : 6;
    float w[KSIZE], b;
#pragma unroll
    for (int d = 0; d < KSIZE; ++d) w[d] = cw[i0 * KSIZE + d];
    b = cb[i0];

#pragma unroll 1
    for (int i = i0; i < i1; ++i) {
        float* hb = hbuf[i & 1];

        // --- 1: update r[0..S-1] (these are next layer's published halo) ---
#pragma unroll
        for (int k = 0; k < S; ++k) {
            float acc = b;
#pragma unroll
            for (int d = 0; d < KSIZE; ++d) {
                const int m = k + d;
                const float v = (m < R) ? r[m] : h[m - R];  // compile-time select
                acc = fmaf(w[d], v, acc);
            }
            r[k] = RELU ? fmaxf(acc, 0.0f) : acc;
        }

        // --- 2: publish updated leading values (32B-aligned slot -> b128/b64) ---
#pragma unroll
        for (int k = 0; k < S; ++k) hb[tid * HSTRIDE + k] = r[k];
        __syncthreads();

        // --- 3: fetch NEXT layer's halo (positions tid*R + R + t) ---
        float hn[6];
#pragma unroll
        for (int t = 0; t < 6; ++t) {
            const int src = tid + (R + t) / R;   // <= tid+2 <= 129
            const int e   = (R + t) % R;
            hn[t] = hb[src * HSTRIDE + e];
        }

        // --- prefetch next layer's weights (uniform -> scalar loads) ---
        float w2[KSIZE], b2;
        const int ip = (i + 1 < i1) ? (i + 1) : i;
#pragma unroll
        for (int d = 0; d < KSIZE; ++d) w2[d] = cw[ip * KSIZE + d];
        b2 = cb[ip];

        // --- 4: update r[S..R-1] (consumes h fetched one layer ago) ---
#pragma unroll
        for (int k = S; k < R; ++k) {
            float acc = b;
#pragma unroll
            for (int d = 0; d < KSIZE; ++d) {
                const int m = k + d;
                const float v = (m < R) ? r[m] : h[m - R];
                acc = fmaf(w[d], v, acc);
            }
            r[k] = RELU ? fmaxf(acc, 0.0f) : acc;
        }

        // --- 5: commit pipelined state ---
#pragma unroll
        for (int t = 0; t < 6; ++t) h[t] = hn[t];
#pragma unroll
        for (int d = 0; d < KSIZE; ++d) w[d] = w2[d];
        b = b2;
    }
}

// Redistribute Ro values/thread -> Rn, re-prime halo from LDS.
// lbuf was last touched >=32 barriers ago, so no leading barrier needed.
template<int Ro, int Rn>
__device__ __forceinline__ void repack(float (&r)[RMAX], float (&h)[6],
                                       float* lbuf, int tid)
{
#pragma unroll
    for (int k = 0; k < Ro; ++k) lbuf[tid * Ro + k] = r[k];
    __syncthreads();
#pragma unroll
    for (int k = 0; k < Rn; ++k) r[k] = lbuf[tid * Rn + k];
#pragma unroll
    for (int t = 0; t < 6; ++t) h[t] = lbuf[tid * Rn + Rn + t];  // <= 128*Rn+5 < 128*Ro
    __syncthreads();
}

__global__ __launch_bounds__(NT) void conv_chain_kernel(
    const float* __restrict__ x,
    const float* __restrict__ conv_w,
    const float* __restrict__ conv_b,
    const float* __restrict__ fc_w,
    const float* __restrict__ fc_b,
    float* __restrict__ out)
{
    __shared__ float hbuf[2][(NT + 2) * HSTRIDE];        // 4.06 KB: halo ring
    __shared__ __align__(16) float lbuf[NT * RMAX + 8];  // 5.53 KB: repack + FC

    const int row = blockIdx.x;
    const int tid = threadIdx.x;

    // Load chunk + initial halo from global; zero-pad past L_IN.
    float r[RMAX], h[6];
    const float* xr = x + (size_t)row * L_IN;
#pragma unroll
    for (int k = 0; k < RMAX; ++k) {
        const int p = tid * RMAX + k;
        r[k] = (p < L_IN) ? xr[p] : 0.0f;
    }
#pragma unroll
    for (int t = 0; t < 6; ++t) {
        const int p = tid * RMAX + RMAX + t;
        h[t] = (p < L_IN) ? xr[p] : 0.0f;
    }

    // Stage plan (len_i = 1388 - 6i must fit in 128*R):
    // i=0:1388<=1408  i=32:1196<=1280  i=64:1004<=1024  i=96:812<=896
    // i=128:620<=640  i=160:428<=512   end len 188 in R=4 layout.
    run_stage<11, true>(r, h, conv_w, conv_b,   0,  32, hbuf, tid);
    repack<11, 10>(r, h, lbuf, tid);
    run_stage<10, true>(r, h, conv_w, conv_b,  32,  64, hbuf, tid);
    repack<10, 8>(r, h, lbuf, tid);
    run_stage< 8, true>(r, h, conv_w, conv_b,  64,  96, hbuf, tid);
    repack< 8, 7>(r, h, lbuf, tid);
    run_stage< 7, true>(r, h, conv_w, conv_b,  96, 128, hbuf, tid);
    repack< 7, 5>(r, h, lbuf, tid);
    run_stage< 5, true>(r, h, conv_w, conv_b, 128, 160, hbuf, tid);
    repack< 5, 4>(r, h, lbuf, tid);
    run_stage< 4, true >(r, h, conv_w, conv_b, 160, 199, hbuf, tid);
    run_stage< 4, false>(r, h, conv_w, conv_b, 199, 200, hbuf, tid);

    // FC(188 -> 91) + sigmoid. r is in R=4 layout: position tid*4 + k.
    __syncthreads();   // all halo-ring reads done before lbuf reuse
#pragma unroll
    for (int k = 0; k < 4; ++k) {
        const int p = tid * 4 + k;
        if (p < FC_IN) lbuf[p] = r[k];
    }
    __syncthreads();

    if (tid < FC_OUT) {
        float acc = fc_b[tid];
        const float4* wp = (const float4*)(fc_w + tid * FC_IN);  // 188*4B rows: 16B-aligned
        const float4* hp = (const float4*)lbuf;
#pragma unroll 4
        for (int q = 0; q < FC_IN / 4; ++q) {
            const float4 hv = hp[q];
            const float4 wv = wp[q];
            acc = fmaf(wv.x, hv.x, acc);
            acc = fmaf(wv.y, hv.y, acc);
            acc = fmaf(wv.z, hv.z, acc);
            acc = fmaf(wv.w, hv.w, acc);
        }
        out[(size_t)row * FC_OUT + tid] = 1.0f / (1.0f + expf(-acc));
    }
}

extern "C" void kernel_launch(void* const* d_in, const int* in_sizes, int n_in,
                              void* d_out, int out_size, void* d_ws, size_t ws_size,
                              hipStream_t stream) {
    const float* x      = (const float*)d_in[0];
    const float* conv_w = (const float*)d_in[1];
    const float* conv_b = (const float*)d_in[2];
    const float* fc_w   = (const float*)d_in[3];
    const float* fc_b   = (const float*)d_in[4];
    float* outp = (float*)d_out;

    const int batch = in_sizes[0] / L_IN;  // 1024 rows, 2 waves each
    conv_chain_kernel<<<batch, NT, 0, stream>>>(x, conv_w, conv_b, fc_w, fc_b, outp);
}

// Round 5
// 135.652 us; speedup vs baseline: 1.7434x; 1.0383x over previous
//
#include <hip/hip_runtime.h>
#include <math.h>

#define N_LAYERS 200
#define KSIZE 7
#define L_IN 1388
#define FC_IN 188
#define FC_OUT 91
#define NT 128        // 2 waves per row, INDEPENDENT between repacks
#define RMAX 13       // stage-0 values per lane: 64*13 = 832 >= 790

// ---- Overlap plan (stage = 32 layers, receptive growth 6*32 = 192) ----
// len(i) = 1388 - 6i. For stage [i0,i1): cut = len(i1)/2.
//   wave0 extended region: [0, cut + 192)          size E = len(i1)/2 + 192
//   wave1 extended region: [cut, len(i0))          size E (equal)
// Each wave computes its extended region independently (shfl halo only);
// garbage beyond the region creeps left 6/layer and reaches exactly the
// owned boundary at stage end. Waves exchange data only at repacks.
//
// stage: layers      len(i1)  cut   E    R
//   0    [0,32)      1196     598   790  13
//   1    [32,64)     1004     502   694  11
//   2    [64,96)      812     406   598  10
//   3    [96,128)     620     310   502   8
//   4    [128,160)    428     214   406   7
//   5    [160,192)    236     118   310   5
//   6    [192,200)    188      94   142   3   (growth 48)

// One stage with R values/lane, shfl-pipelined halo (round-3 verified):
//  - r[0..R-1]: positions base + lane*R + k of current layer's input.
//  - h[0..5]:   positions base + lane*R + R + t, fetched PREVIOUS layer.
//  - Ascending in-place update is safe (output k overwrites input k only).
//  - After updating r[0..S-1] they are next layer's inputs -> issue the
//    next halo shfl there; latency hidden behind k=S..R-1 updates.
template<int R, bool RELU>
__device__ __forceinline__ void run_stage(float (&r)[RMAX], float (&h)[6],
                                          const float* __restrict__ cw,
                                          const float* __restrict__ cb,
                                          int i0, int i1)
{
    constexpr int S = (R < 6) ? R : 6;
    float w[KSIZE], b;
#pragma unroll
    for (int d = 0; d < KSIZE; ++d) w[d] = cw[i0 * KSIZE + d];
    b = cb[i0];

#pragma unroll 1
    for (int i = i0; i < i1; ++i) {
        // update k = 0..S-1 (consumes h when R < 12)
#pragma unroll
        for (int k = 0; k < S; ++k) {
            float acc = b;
#pragma unroll
            for (int d = 0; d < KSIZE; ++d) {
                const int m = k + d;
                const float v = (m < R) ? r[m] : h[m - R];  // compile-time select
                acc = fmaf(w[d], v, acc);
            }
            r[k] = RELU ? fmaxf(acc, 0.0f) : acc;
        }

        // issue next layer's halo fetch (just-updated r[0..5] of lane+1/+2);
        // out-of-range lanes return garbage -> lands only in garbage zone.
        float hn[6];
#pragma unroll
        for (int t = 0; t < 6; ++t)
            hn[t] = __shfl_down(r[t % R], 1 + t / R);

        // prefetch next layer's weights (uniform -> scalar loads)
        float w2[KSIZE], b2;
        const int ip = (i + 1 < i1) ? (i + 1) : i;
#pragma unroll
        for (int d = 0; d < KSIZE; ++d) w2[d] = cw[ip * KSIZE + d];
        b2 = cb[ip];

        // update k = S..R-1 (consumes h fetched one layer ago)
#pragma unroll
        for (int k = S; k < R; ++k) {
            float acc = b;
#pragma unroll
            for (int d = 0; d < KSIZE; ++d) {
                const int m = k + d;
                const float v = (m < R) ? r[m] : h[m - R];
                acc = fmaf(w[d], v, acc);
            }
            r[k] = RELU ? fmaxf(acc, 0.0f) : acc;
        }

        // commit pipelined state
#pragma unroll
        for (int t = 0; t < 6; ++t) h[t] = hn[t];
#pragma unroll
        for (int d = 0; d < KSIZE; ++d) w[d] = w2[d];
        b = b2;
    }
}

// Cross-wave repack at a stage boundary. Each wave writes its OWNED valid
// values [base_o, bound) at global row positions, barrier, then reads its
// next extended region from [base_n, ...) and re-primes the halo.
// Trailing barrier protects lbuf against the next repack's writes.
template<int Ro, int Rn>
__device__ __forceinline__ void repack(float (&r)[RMAX], float (&h)[6],
                                       float* lbuf, int lane,
                                       int base_o, int bound, int base_n)
{
#pragma unroll
    for (int k = 0; k < Ro; ++k) {
        const int g = base_o + lane * Ro + k;
        if (g < bound) lbuf[g] = r[k];
    }
    __syncthreads();
#pragma unroll
    for (int k = 0; k < Rn; ++k) r[k] = lbuf[base_n + lane * Rn + k];
#pragma unroll
    for (int t = 0; t < 6; ++t) h[t] = lbuf[base_n + lane * Rn + Rn + t];
    __syncthreads();
}

__global__ __launch_bounds__(NT) void conv_chain_kernel(
    const float* __restrict__ x,
    const float* __restrict__ conv_w,
    const float* __restrict__ conv_b,
    const float* __restrict__ fc_w,
    const float* __restrict__ fc_b,
    float* __restrict__ out)
{
    // max write 1196 floats; max read overshoot 502+64*11+5 = 1211 -> 1216.
    __shared__ __align__(16) float lbuf[1216];

    const int row  = blockIdx.x;
    const int tid  = threadIdx.x;
    const int lane = tid & 63;
    const int wid  = tid >> 6;

    // Stage-0 load straight from global (wave0 base 0, wave1 base 598).
    float r[RMAX], h[6];
    const float* xr = x + (size_t)row * L_IN;
    const int base0 = wid ? 598 : 0;
#pragma unroll
    for (int k = 0; k < 13; ++k) {
        const int p = base0 + lane * 13 + k;
        r[k] = (p < L_IN) ? xr[p] : 0.0f;
    }
#pragma unroll
    for (int t = 0; t < 6; ++t) {
        const int p = base0 + lane * 13 + 13 + t;
        h[t] = (p < L_IN) ? xr[p] : 0.0f;
    }

    run_stage<13, true>(r, h, conv_w, conv_b,   0,  32);
    repack<13, 11>(r, h, lbuf, lane, wid ? 598 : 0, wid ? 1196 : 598, wid ? 502 : 0);
    run_stage<11, true>(r, h, conv_w, conv_b,  32,  64);
    repack<11, 10>(r, h, lbuf, lane, wid ? 502 : 0, wid ? 1004 : 502, wid ? 406 : 0);
    run_stage<10, true>(r, h, conv_w, conv_b,  64,  96);
    repack<10,  8>(r, h, lbuf, lane, wid ? 406 : 0, wid ?  812 : 406, wid ? 310 : 0);
    run_stage< 8, true>(r, h, conv_w, conv_b,  96, 128);
    repack< 8,  7>(r, h, lbuf, lane, wid ? 310 : 0, wid ?  620 : 310, wid ? 214 : 0);
    run_stage< 7, true>(r, h, conv_w, conv_b, 128, 160);
    repack< 7,  5>(r, h, lbuf, lane, wid ? 214 : 0, wid ?  428 : 214, wid ? 118 : 0);
    run_stage< 5, true>(r, h, conv_w, conv_b, 160, 192);
    repack< 5,  3>(r, h, lbuf, lane, wid ? 118 : 0, wid ?  236 : 118, wid ?  94 : 0);
    run_stage< 3, true >(r, h, conv_w, conv_b, 192, 199);
    run_stage< 3, false>(r, h, conv_w, conv_b, 199, 200);

    // Gather the 188 final values (wave0 owns [0,94), wave1 [94,188)).
    {
        const int bo = wid ? 94 : 0;
        const int bd = wid ? 188 : 94;
#pragma unroll
        for (int k = 0; k < 3; ++k) {
            const int g = bo + lane * 3 + k;
            if (g < bd) lbuf[g] = r[k];
        }
    }
    __syncthreads();

    // FC(188 -> 91) + sigmoid.
    if (tid < FC_OUT) {
        float acc = fc_b[tid];
        const float4* wp = (const float4*)(fc_w + tid * FC_IN);  // 188*4B rows: 16B-aligned
        const float4* hp = (const float4*)lbuf;
#pragma unroll 4
        for (int q = 0; q < FC_IN / 4; ++q) {
            const float4 hv = hp[q];
            const float4 wv = wp[q];
            acc = fmaf(wv.x, hv.x, acc);
            acc = fmaf(wv.y, hv.y, acc);
            acc = fmaf(wv.z, hv.z, acc);
            acc = fmaf(wv.w, hv.w, acc);
        }
        out[(size_t)row * FC_OUT + tid] = 1.0f / (1.0f + expf(-acc));
    }
}

extern "C" void kernel_launch(void* const* d_in, const int* in_sizes, int n_in,
                              void* d_out, int out_size, void* d_ws, size_t ws_size,
                              hipStream_t stream) {
    const float* x      = (const float*)d_in[0];
    const float* conv_w = (const float*)d_in[1];
    const float* conv_b = (const float*)d_in[2];
    const float* fc_w   = (const float*)d_in[3];
    const float* fc_b   = (const float*)d_in[4];
    float* outp = (float*)d_out;

    const int batch = in_sizes[0] / L_IN;  // 1024 rows, 2 independent waves each
    conv_chain_kernel<<<batch, NT, 0, stream>>>(x, conv_w, conv_b, fc_w, fc_b, outp);
}